// Round 1
// 476.454 us; speedup vs baseline: 12.2924x; 12.2924x over previous
//
#include <hip/hip_runtime.h>

#define LSEQ 96
#define DM 256
#define NH 8
#define DH 32
#define WIN 16

typedef unsigned short u16;
typedef unsigned int u32;
typedef __attribute__((ext_vector_type(8))) short bf16x8;
typedef __attribute__((ext_vector_type(4))) float f32x4;

#define MFMA(a, b, c) __builtin_amdgcn_mfma_f32_16x16x32_bf16((a), (b), (c), 0, 0, 0)

__device__ __forceinline__ u16 bf16_rne(float x) {
    u32 u = __float_as_uint(x);
    u32 r = (u + 0x7FFFu + ((u >> 16) & 1u)) >> 16;
    return (u16)r;
}
__device__ __forceinline__ float bf16f(u16 h) {
    return __uint_as_float(((u32)h) << 16);
}

// ---------------------------------------------------------------------------
// prep_weights: split each W (fp32 256x256) into hi/lo bf16 and store in
// MFMA-B-fragment-native tiled order:
//   element f = ((mat*16 + ntile)*8 + kstep)*512 + lane*8 + j
//   holds W_mat[k][col],  k = kstep*32 + (lane>>4)*8 + j,  col = ntile*16 + (lane&15)
// so one wave's B-fragment load is a contiguous, coalesced 1KB read.
// Needs 1 MB of d_ws (512KB hi + 512KB lo).
// ---------------------------------------------------------------------------
__global__ __launch_bounds__(256) void prep_weights(
    const float* __restrict__ Wq, const float* __restrict__ Wk,
    const float* __restrict__ Wv, const float* __restrict__ Wo,
    u16* __restrict__ wth, u16* __restrict__ wtl)
{
    int f = blockIdx.x * 256 + threadIdx.x;      // 0 .. 262143
    int j  = f & 7;
    int l  = (f >> 3) & 63;
    int ks = (f >> 9) & 7;
    int nt = (f >> 12) & 15;
    int m  = f >> 16;
    const float* W = (m == 0) ? Wq : (m == 1) ? Wk : (m == 2) ? Wv : Wo;
    int k   = ks * 32 + ((l >> 4) << 3) + j;
    int col = nt * 16 + (l & 15);
    float x = W[k * 256 + col];
    u16 hi = bf16_rne(x);
    wth[f] = hi;
    wtl[f] = bf16_rne(x - bf16f(hi));
}

// ---------------------------------------------------------------------------
// fused_attn: one block per sequence (1024 blocks), 512 threads (8 waves).
// All contractions via mfma_f32_16x16x32_bf16 with hi/lo split x3 products
// (error ~2^-16 rel -> absmax dominated by __expf, same as fp32 version).
// LDS regions (all row strides padded so fragment reads are <=2-way banked):
//   XH/XL  [96][264] bf16          2*50688 B
//   R      39936 B, time-shared:
//     QKV/S phase: QH,QL,KH,KL [96][40]
//     P phase:     PH,PL       [96][104]
//     A phase:     AH,AL       [96][40]
//   VT     VTH,VTL [32][104]       13312 B   (V stored transposed for PV B-op)
//   rbh    [96] f32                  384 B
// total 155008 B  (1 block/CU)
// ---------------------------------------------------------------------------
__global__ __launch_bounds__(512, 2) void fused_attn(
    const float* __restrict__ Z, const u16* __restrict__ wth,
    const u16* __restrict__ wtl, const float* __restrict__ rb,
    float* __restrict__ out)
{
    __shared__ u16 XH[96 * 264];
    __shared__ u16 XL[96 * 264];
    __shared__ u16 R[19968];          // 39936 B shared region
    __shared__ u16 VTm[2 * 32 * 104]; // VTH @0, VTL @3328
    __shared__ float rbh[96];

    const int tid  = threadIdx.x;
    const int n    = blockIdx.x;
    const int w    = tid >> 6;
    const int lane = tid & 63;
    const int g    = lane >> 4;   // 16-lane group 0..3
    const int qr   = lane & 15;

    u16* const QH = R;              u16* const QL = R + 3840;
    u16* const KH = R + 7680;       u16* const KL = R + 11520;
    u16* const PH = R;              u16* const PL = R + 9984;
    u16* const AH = R;              u16* const AL = R + 3840;
    u16* const VTH = VTm;           u16* const VTL = VTm + 3328;

    // ---- stage X as hi/lo bf16 into LDS (coalesced float4 reads) ----
    const float4* Zv = (const float4*)(Z + (size_t)n * (LSEQ * DM));
#pragma unroll
    for (int r2 = 0; r2 < 12; ++r2) {
        int e = tid + (r2 << 9);          // 0..6143 (float4 index)
        float4 x = Zv[e];
        int row = e >> 6;
        int c4  = e & 63;
        u16 h0 = bf16_rne(x.x), h1 = bf16_rne(x.y);
        u16 h2 = bf16_rne(x.z), h3 = bf16_rne(x.w);
        ushort4 hv = {h0, h1, h2, h3};
        ushort4 lv = {bf16_rne(x.x - bf16f(h0)), bf16_rne(x.y - bf16f(h1)),
                      bf16_rne(x.z - bf16f(h2)), bf16_rne(x.w - bf16f(h3))};
        *(ushort4*)&XH[row * 264 + c4 * 4] = hv;
        *(ushort4*)&XL[row * 264 + c4 * 4] = lv;
    }

    f32x4 oacc[12];
#pragma unroll
    for (int i = 0; i < 12; ++i) oacc[i] = (f32x4){0.f, 0.f, 0.f, 0.f};

    const float scale = 0.17677669529663687f;  // 1/sqrt(32)

    for (int h = 0; h < NH; ++h) {
        __syncthreads();  // protect R/VT/rbh reuse across head iterations
        if (tid < 96) rbh[tid] = rb[h * 96 + tid];

        // ===== QKV: 36 (16x16) tiles over {Wq,Wk,Wv} x 2 ncols x 6 mrows =====
        {
            int start = (w < 4) ? w * 5 : 20 + (w - 4) * 4;
            int cnt   = (w < 4) ? 5 : 4;
            bf16x8 bhr[8], blr[8];
            int curcol = -1;
            for (int t = start; t < start + cnt; ++t) {
                int col = t / 6;            // 0..5 (mat*2 + local ncol)
                int m   = t - col * 6;      // 0..5
                int mat = col >> 1;
                if (col != curcol) {        // cache B frags across m-tiles
                    curcol = col;
                    int nt = h * 2 + (col & 1);
                    size_t boff = (size_t)(((mat * 16 + nt) * 8) * 64 + lane) * 8;
#pragma unroll
                    for (int ks = 0; ks < 8; ++ks) {
                        bhr[ks] = *(const bf16x8*)(wth + boff + ((size_t)ks << 9));
                        blr[ks] = *(const bf16x8*)(wtl + boff + ((size_t)ks << 9));
                    }
                }
                f32x4 acc = {0.f, 0.f, 0.f, 0.f};
                const u16* xh = &XH[(m * 16 + qr) * 264 + g * 8];
                const u16* xl = &XL[(m * 16 + qr) * 264 + g * 8];
#pragma unroll
                for (int ks = 0; ks < 8; ++ks) {
                    bf16x8 ah = *(const bf16x8*)(xh + ks * 32);
                    bf16x8 al = *(const bf16x8*)(xl + ks * 32);
                    acc = MFMA(al, bhr[ks], acc);
                    acc = MFMA(ah, blr[ks], acc);
                    acc = MFMA(ah, bhr[ks], acc);
                }
                // C frag: col = qr (head-dim), row = m*16 + g*4 + r (seq pos)
                int cl = (col & 1) * 16 + qr;   // 0..31 within head
                int i0 = m * 16 + g * 4;
                if (mat < 2) {
                    u16* dh = (mat == 0) ? QH : KH;
                    u16* dl = (mat == 0) ? QL : KL;
#pragma unroll
                    for (int r = 0; r < 4; ++r) {
                        float v = acc[r];
                        u16 hi = bf16_rne(v);
                        dh[(i0 + r) * 40 + cl] = hi;
                        dl[(i0 + r) * 40 + cl] = bf16_rne(v - bf16f(hi));
                    }
                } else {  // V -> transposed store VT[c][j], 4 consecutive j
                    u16 hs[4], ls[4];
#pragma unroll
                    for (int r = 0; r < 4; ++r) {
                        float v = acc[r];
                        hs[r] = bf16_rne(v);
                        ls[r] = bf16_rne(v - bf16f(hs[r]));
                    }
                    *(ushort4*)&VTH[cl * 104 + i0] = (ushort4){hs[0], hs[1], hs[2], hs[3]};
                    *(ushort4*)&VTL[cl * 104 + i0] = (ushort4){ls[0], ls[1], ls[2], ls[3]};
                }
            }
        }
        __syncthreads();  // (1) QKV visible

        // ===== S = Q K^T + in-register softmax (waves 0..5, strip m = w) =====
        u32 pw[6][4];
        if (w < 6) {
            f32x4 sacc[6];
            const u16* qh = &QH[(w * 16 + qr) * 40 + g * 8];
            bf16x8 ah = *(const bf16x8*)qh;
            bf16x8 al = *(const bf16x8*)(qh + 3840);
#pragma unroll
            for (int t = 0; t < 6; ++t) {
                const u16* kh = &KH[(t * 16 + qr) * 40 + g * 8];
                bf16x8 bh = *(const bf16x8*)kh;
                bf16x8 bl = *(const bf16x8*)(kh + 3840);
                f32x4 acc = {0.f, 0.f, 0.f, 0.f};
                acc = MFMA(al, bh, acc);
                acc = MFMA(ah, bl, acc);
                acc = MFMA(ah, bh, acc);
                sacc[t] = acc;
            }
            // softmax: row i spread over 16 lanes (cols j = t*16 + qr)
#pragma unroll
            for (int r = 0; r < 4; ++r) {
                int i = w * 16 + g * 4 + r;
                float v[6];
                float mx = -3.0e38f;
#pragma unroll
                for (int t = 0; t < 6; ++t) {
                    int j = t * 16 + qr;
                    int diff = i - j; if (diff < 0) diff += 96;
                    int dc = min(diff, 96 - diff);
                    float val = (dc <= WIN) ? (sacc[t][r] * scale + rbh[diff]) : -3.0e38f;
                    v[t] = val;
                    mx = fmaxf(mx, val);
                }
                mx = fmaxf(mx, __shfl_xor(mx, 1));
                mx = fmaxf(mx, __shfl_xor(mx, 2));
                mx = fmaxf(mx, __shfl_xor(mx, 4));
                mx = fmaxf(mx, __shfl_xor(mx, 8));
                float s = 0.f;
#pragma unroll
                for (int t = 0; t < 6; ++t) { float e = __expf(v[t] - mx); v[t] = e; s += e; }
                s += __shfl_xor(s, 1);
                s += __shfl_xor(s, 2);
                s += __shfl_xor(s, 4);
                s += __shfl_xor(s, 8);
                float inv = 1.f / s;
#pragma unroll
                for (int t = 0; t < 6; ++t) {
                    float p = v[t] * inv;
                    u16 hi = bf16_rne(p);
                    u16 lo = bf16_rne(p - bf16f(hi));
                    pw[t][r] = (u32)hi | ((u32)lo << 16);
                }
            }
        }
        __syncthreads();  // (2) all QK reads done before P overwrites region
        if (w < 6) {
#pragma unroll
            for (int r = 0; r < 4; ++r) {
                int i = w * 16 + g * 4 + r;
#pragma unroll
                for (int t = 0; t < 6; ++t) {
                    int j = t * 16 + qr;
                    PH[i * 104 + j] = (u16)(pw[t][r] & 0xFFFFu);
                    PL[i * 104 + j] = (u16)(pw[t][r] >> 16);
                }
            }
        }
        __syncthreads();  // (3) P visible

        // ===== PV: O = P @ V, 12 tiles (6m x 2nc) =====
        {
            auto pv_tile = [&](int m, int nc) -> f32x4 {
                f32x4 acc = {0.f, 0.f, 0.f, 0.f};
                const u16* ph = &PH[(m * 16 + qr) * 104 + g * 8];
                const u16* vh = &VTH[(nc * 16 + qr) * 104 + g * 8];
#pragma unroll
                for (int ks = 0; ks < 3; ++ks) {
                    bf16x8 pah = *(const bf16x8*)(ph + ks * 32);
                    bf16x8 pal = *(const bf16x8*)(ph + 9984 + ks * 32);
                    bf16x8 vbh = *(const bf16x8*)(vh + ks * 32);
                    bf16x8 vbl = *(const bf16x8*)(vh + 3328 + ks * 32);
                    acc = MFMA(pal, vbh, acc);
                    acc = MFMA(pah, vbl, acc);
                    acc = MFMA(pah, vbh, acc);
                }
                return acc;
            };
            int t0 = (w < 4) ? (w * 2) : (8 + (w - 4));
            int tc = (w < 4) ? 2 : 1;
            int m0 = t0 >> 1, nc0 = t0 & 1;
            int m1 = (t0 + 1) >> 1, nc1 = (t0 + 1) & 1;
            f32x4 ov0 = pv_tile(m0, nc0);
            f32x4 ov1 = {0.f, 0.f, 0.f, 0.f};
            if (tc > 1) ov1 = pv_tile(m1, nc1);
            __syncthreads();  // (4) all P/VT reads done before A overwrites
            auto pv_write = [&](int m, int nc, f32x4 ov) {
                int i0 = m * 16 + g * 4;
                int c  = nc * 16 + qr;
#pragma unroll
                for (int r = 0; r < 4; ++r) {
                    float vv = ov[r];
                    u16 hi = bf16_rne(vv);
                    AH[(i0 + r) * 40 + c] = hi;
                    AL[(i0 + r) * 40 + c] = bf16_rne(vv - bf16f(hi));
                }
            };
            pv_write(m0, nc0, ov0);
            if (tc > 1) pv_write(m1, nc1, ov1);
        }
        __syncthreads();  // (5) A visible

        // ===== accumulate A @ Wo[h*32:(h+1)*32, :] : 12 tiles/wave =====
        {
#pragma unroll
            for (int ntl = 0; ntl < 2; ++ntl) {
                int nt = w * 2 + ntl;
                size_t boff = (size_t)((((3 * 16 + nt) * 8 + h) * 64) + lane) * 8;
                bf16x8 bh = *(const bf16x8*)(wth + boff);
                bf16x8 bl = *(const bf16x8*)(wtl + boff);
#pragma unroll
                for (int m = 0; m < 6; ++m) {
                    const u16* ahp = &AH[(m * 16 + qr) * 40 + g * 8];
                    bf16x8 ah = *(const bf16x8*)ahp;
                    bf16x8 al = *(const bf16x8*)(ahp + 3840);
                    f32x4 acc = oacc[ntl * 6 + m];
                    acc = MFMA(al, bh, acc);
                    acc = MFMA(ah, bl, acc);
                    acc = MFMA(ah, bh, acc);
                    oacc[ntl * 6 + m] = acc;
                }
            }
        }
    }

    // ===== final store (fp32, coalesced 64B per 16-lane group) =====
    float* on = out + (size_t)n * (LSEQ * DM);
#pragma unroll
    for (int ntl = 0; ntl < 2; ++ntl) {
        int d = (w * 2 + ntl) * 16 + qr;
#pragma unroll
        for (int m = 0; m < 6; ++m) {
#pragma unroll
            for (int r = 0; r < 4; ++r) {
                int i = m * 16 + g * 4 + r;
                on[i * 256 + d] = oacc[ntl * 6 + m][r];
            }
        }
    }
}

extern "C" void kernel_launch(void* const* d_in, const int* in_sizes, int n_in,
                              void* d_out, int out_size, void* d_ws, size_t ws_size,
                              hipStream_t stream) {
    const float* Z  = (const float*)d_in[0];
    const float* Wq = (const float*)d_in[1];
    const float* Wk = (const float*)d_in[2];
    const float* Wv = (const float*)d_in[3];
    const float* Wo = (const float*)d_in[4];
    const float* Wo_unused = Wo; (void)Wo_unused;
    const float* rbp = (const float*)d_in[5];
    float* out = (float*)d_out;

    // workspace: 512KB hi + 512KB lo of fragment-tiled split weights
    u16* wth = (u16*)d_ws;
    u16* wtl = wth + 262144;

    prep_weights<<<1024, 256, 0, stream>>>(Wq, Wk, Wv, Wo, wth, wtl);
    fused_attn<<<1024, 512, 0, stream>>>(Z, wth, wtl, rbp, out);
}

// Round 2
// 369.514 us; speedup vs baseline: 15.8498x; 1.2894x over previous
//
#include <hip/hip_runtime.h>

#define LSEQ 96
#define DM 256
#define NH 8
#define DH 32
#define WIN 16

typedef unsigned short u16;
typedef unsigned int u32;
typedef _Float16 f16;
typedef __attribute__((ext_vector_type(4))) _Float16 f16x4;
typedef __attribute__((ext_vector_type(8))) _Float16 f16x8;
typedef __attribute__((ext_vector_type(4))) float f32x4;

#define MFMA(a, b, c) __builtin_amdgcn_mfma_f32_16x16x32_f16((a), (b), (c), 0, 0, 0)

// ---------------------------------------------------------------------------
// prep_weights: convert each W (fp32 256x256) to fp16 in MFMA-B-fragment-
// native tiled order:
//   element f = ((mat*16 + ntile)*8 + kstep)*512 + lane*8 + j
//   holds W_mat[k][col],  k = kstep*32 + (lane>>4)*8 + j,  col = ntile*16 + (lane&15)
// One wave's B-fragment load is a contiguous, coalesced 1KB read.
// Needs 512KB of d_ws.
// ---------------------------------------------------------------------------
__global__ __launch_bounds__(256) void prep_weights(
    const float* __restrict__ Wq, const float* __restrict__ Wk,
    const float* __restrict__ Wv, const float* __restrict__ Wo,
    f16* __restrict__ wt)
{
    int f = blockIdx.x * 256 + threadIdx.x;      // 0 .. 262143
    int j  = f & 7;
    int l  = (f >> 3) & 63;
    int ks = (f >> 9) & 7;
    int nt = (f >> 12) & 15;
    int m  = f >> 16;
    const float* W = (m == 0) ? Wq : (m == 1) ? Wk : (m == 2) ? Wv : Wo;
    int k   = ks * 32 + ((l >> 4) << 3) + j;
    int col = nt * 16 + (l & 15);
    wt[f] = (f16)W[k * 256 + col];
}

// ---------------------------------------------------------------------------
// fused_attn: one block per sequence (1024 blocks), 512 threads (8 waves).
// All contractions via mfma_f32_16x16x32_f16, single fp16 product (rel err
// 2^-11, ~4x margin under the 2^-7 tolerance).
// LDS (all row strides 16B-aligned so fragment reads are ds_read_b128):
//   XH  [96][264] f16     50688 B
//   R   9984 f16          19968 B, time-shared:
//     QKV/S phase: Q[96][40] @0, K[96][40] @3840
//     P phase:     P[96][104] @0
//     A phase:     A[96][40] @0
//   VT  [32][104] f16      6656 B  (V transposed for PV B-operand)
//   rbh [96] f32            384 B
// total 77696 B  ->  2 blocks/CU (16 waves/CU, 50% occupancy)
// ---------------------------------------------------------------------------
__global__ __launch_bounds__(512, 4) void fused_attn(
    const float* __restrict__ Z, const f16* __restrict__ wt,
    const float* __restrict__ rb, float* __restrict__ out)
{
    __shared__ f16 XH[96 * 264];
    __shared__ f16 R[9984];
    __shared__ f16 VT[32 * 104];
    __shared__ float rbh[96];

    const int tid  = threadIdx.x;
    const int n    = blockIdx.x;
    const int w    = tid >> 6;
    const int lane = tid & 63;
    const int g    = lane >> 4;   // 16-lane group 0..3
    const int qr   = lane & 15;

    f16* const QH = R;
    f16* const KH = R + 3840;
    f16* const PH = R;
    f16* const AH = R;

    // ---- stage X as fp16 into LDS (coalesced float4 reads) ----
    const float4* Zv = (const float4*)(Z + (size_t)n * (LSEQ * DM));
#pragma unroll
    for (int r2 = 0; r2 < 12; ++r2) {
        int e = tid + (r2 << 9);          // 0..6143 (float4 index)
        float4 x = Zv[e];
        int row = e >> 6;
        int c4  = e & 63;
        f16x4 hv = {(f16)x.x, (f16)x.y, (f16)x.z, (f16)x.w};
        *(f16x4*)&XH[row * 264 + c4 * 4] = hv;
    }

    f32x4 oacc[12];
#pragma unroll
    for (int i = 0; i < 12; ++i) oacc[i] = (f32x4){0.f, 0.f, 0.f, 0.f};

    const float scale = 0.17677669529663687f;  // 1/sqrt(32)

    for (int h = 0; h < NH; ++h) {
        __syncthreads();  // protect R/VT/rbh reuse across head iterations
        if (tid < 96) rbh[tid] = rb[h * 96 + tid];

        // ===== QKV: 36 (16x16) tiles over {Wq,Wk,Wv} x 2 ncols x 6 mrows =====
        {
            int start = (w < 4) ? w * 5 : 20 + (w - 4) * 4;
            int remaining = (w < 4) ? 5 : 4;
            int t = start;
            while (remaining > 0) {
                int col = t / 6;            // 0..5 (mat*2 + local ncol)
                int m0  = t - col * 6;
                int run = 6 - m0; if (run > remaining) run = remaining;
                int mat = col >> 1;
                int nt  = h * 2 + (col & 1);
                const f16* bp = wt + (size_t)(((mat * 16 + nt) * 8) * 64 + lane) * 8;
                f16x8 B[8];
#pragma unroll
                for (int ks = 0; ks < 8; ++ks)
                    B[ks] = *(const f16x8*)(bp + ((size_t)ks << 9));
                for (int mi = 0; mi < run; ++mi) {
                    int m = m0 + mi;
                    const f16* xp = &XH[(m * 16 + qr) * 264 + g * 8];
                    f32x4 a0 = {0.f, 0.f, 0.f, 0.f};
                    f32x4 a1 = {0.f, 0.f, 0.f, 0.f};
#pragma unroll
                    for (int ks = 0; ks < 8; ks += 2) {   // two chains of 4
                        a0 = MFMA(*(const f16x8*)(xp + ks * 32),       B[ks],     a0);
                        a1 = MFMA(*(const f16x8*)(xp + (ks + 1) * 32), B[ks + 1], a1);
                    }
                    f32x4 acc = a0 + a1;
                    // C frag: col = qr (head-dim), row = m*16 + g*4 + r (seq pos)
                    int cl = (col & 1) * 16 + qr;   // 0..31 within head
                    int i0 = m * 16 + g * 4;
                    if (mat < 2) {
                        f16* d = (mat == 0) ? QH : KH;
#pragma unroll
                        for (int r = 0; r < 4; ++r)
                            d[(i0 + r) * 40 + cl] = (f16)acc[r];
                    } else {  // V -> transposed store VT[c][i], 4 consecutive i
                        f16x4 vv = {(f16)acc[0], (f16)acc[1], (f16)acc[2], (f16)acc[3]};
                        *(f16x4*)&VT[cl * 104 + i0] = vv;
                    }
                }
                t += run; remaining -= run;
            }
        }
        __syncthreads();  // (1) QKV visible

        // ===== S = Q K^T + in-register softmax (waves 0..5, strip m = w) =====
        f16 pv[6][4];
        if (w < 6) {
            f32x4 sacc[6];
            f16x8 aq = *(const f16x8*)&QH[(w * 16 + qr) * 40 + g * 8];
#pragma unroll
            for (int tt = 0; tt < 6; ++tt) {
                f32x4 acc = {0.f, 0.f, 0.f, 0.f};
                acc = MFMA(aq, *(const f16x8*)&KH[(tt * 16 + qr) * 40 + g * 8], acc);
                sacc[tt] = acc;
            }
            // softmax: row i spread over 16 lanes (cols j = tt*16 + qr)
#pragma unroll
            for (int r = 0; r < 4; ++r) {
                int i = w * 16 + g * 4 + r;
                float v[6];
                float mx = -3.0e38f;
#pragma unroll
                for (int tt = 0; tt < 6; ++tt) {
                    int j = tt * 16 + qr;
                    int diff = i - j; if (diff < 0) diff += 96;
                    int dc = min(diff, 96 - diff);
                    float val = (dc <= WIN) ? (sacc[tt][r] * scale + rbh[diff]) : -3.0e38f;
                    v[tt] = val;
                    mx = fmaxf(mx, val);
                }
                mx = fmaxf(mx, __shfl_xor(mx, 1));
                mx = fmaxf(mx, __shfl_xor(mx, 2));
                mx = fmaxf(mx, __shfl_xor(mx, 4));
                mx = fmaxf(mx, __shfl_xor(mx, 8));
                float s = 0.f;
#pragma unroll
                for (int tt = 0; tt < 6; ++tt) { float e = __expf(v[tt] - mx); v[tt] = e; s += e; }
                s += __shfl_xor(s, 1);
                s += __shfl_xor(s, 2);
                s += __shfl_xor(s, 4);
                s += __shfl_xor(s, 8);
                float inv = 1.f / s;
#pragma unroll
                for (int tt = 0; tt < 6; ++tt) pv[tt][r] = (f16)(v[tt] * inv);
            }
        }
        __syncthreads();  // (2) all Q/K reads done before P overwrites region
        if (w < 6) {
#pragma unroll
            for (int r = 0; r < 4; ++r) {
                int i = w * 16 + g * 4 + r;
#pragma unroll
                for (int tt = 0; tt < 6; ++tt)
                    PH[i * 104 + tt * 16 + qr] = pv[tt][r];
            }
        }
        __syncthreads();  // (3) P visible

        // ===== PV: O = P @ V, 12 tiles (6m x 2nc) =====
        {
            auto pv_tile = [&](int m, int nc) -> f32x4 {
                const f16* pp = &PH[(m * 16 + qr) * 104 + g * 8];
                const f16* vp = &VT[(nc * 16 + qr) * 104 + g * 8];
                f32x4 a0 = {0.f, 0.f, 0.f, 0.f};
                f32x4 a1 = {0.f, 0.f, 0.f, 0.f};
                a0 = MFMA(*(const f16x8*)(pp),      *(const f16x8*)(vp),      a0);
                a1 = MFMA(*(const f16x8*)(pp + 32), *(const f16x8*)(vp + 32), a1);
                a0 = MFMA(*(const f16x8*)(pp + 64), *(const f16x8*)(vp + 64), a0);
                return a0 + a1;
            };
            int t0 = (w < 4) ? (w * 2) : (8 + (w - 4));
            int tc = (w < 4) ? 2 : 1;
            int m0 = t0 >> 1, nc0 = t0 & 1;
            int m1 = (t0 + 1) >> 1, nc1 = (t0 + 1) & 1;
            f32x4 ov0 = pv_tile(m0, nc0);
            f32x4 ov1 = {0.f, 0.f, 0.f, 0.f};
            if (tc > 1) ov1 = pv_tile(m1, nc1);
            __syncthreads();  // (4) all P/VT reads done before A overwrites
            auto pv_write = [&](int m, int nc, f32x4 ov) {
                int i0 = m * 16 + g * 4;
                int c  = nc * 16 + qr;
#pragma unroll
                for (int r = 0; r < 4; ++r)
                    AH[(i0 + r) * 40 + c] = (f16)ov[r];
            };
            pv_write(m0, nc0, ov0);
            if (tc > 1) pv_write(m1, nc1, ov1);
        }
        __syncthreads();  // (5) A visible

        // ===== accumulate A @ Wo[h*32:(h+1)*32, :] : 12 indep tiles/wave =====
        {
            f16x8 afr[6];
#pragma unroll
            for (int m = 0; m < 6; ++m)
                afr[m] = *(const f16x8*)&AH[(m * 16 + qr) * 40 + g * 8];
#pragma unroll
            for (int ntl = 0; ntl < 2; ++ntl) {
                int nt = w * 2 + ntl;
                const f16x8 bh = *(const f16x8*)(wt +
                    (size_t)((((3 * 16 + nt) * 8 + h) * 64) + lane) * 8);
#pragma unroll
                for (int m = 0; m < 6; ++m)
                    oacc[ntl * 6 + m] = MFMA(afr[m], bh, oacc[ntl * 6 + m]);
            }
        }
    }

    // ===== final store (fp32, coalesced 64B per 16-lane group) =====
    float* on = out + (size_t)n * (LSEQ * DM);
#pragma unroll
    for (int ntl = 0; ntl < 2; ++ntl) {
        int d = (w * 2 + ntl) * 16 + qr;
#pragma unroll
        for (int m = 0; m < 6; ++m) {
#pragma unroll
            for (int r = 0; r < 4; ++r) {
                int i = m * 16 + g * 4 + r;
                on[i * 256 + d] = oacc[ntl * 6 + m][r];
            }
        }
    }
}

extern "C" void kernel_launch(void* const* d_in, const int* in_sizes, int n_in,
                              void* d_out, int out_size, void* d_ws, size_t ws_size,
                              hipStream_t stream) {
    const float* Z  = (const float*)d_in[0];
    const float* Wq = (const float*)d_in[1];
    const float* Wk = (const float*)d_in[2];
    const float* Wv = (const float*)d_in[3];
    const float* Wo = (const float*)d_in[4];
    const float* rbp = (const float*)d_in[5];
    float* out = (float*)d_out;

    // workspace: 512KB of fragment-tiled fp16 weights
    f16* wt = (f16*)d_ws;

    prep_weights<<<1024, 256, 0, stream>>>(Wq, Wk, Wv, Wo, wt);
    fused_attn<<<1024, 512, 0, stream>>>(Z, wt, rbp, out);
}

// Round 3
// 340.096 us; speedup vs baseline: 17.2209x; 1.0865x over previous
//
#include <hip/hip_runtime.h>

#define LSEQ 96
#define DM 256
#define NH 8
#define DH 32
#define WIN 16

typedef unsigned short u16;
typedef unsigned int u32;
typedef _Float16 f16;
typedef __attribute__((ext_vector_type(4))) _Float16 f16x4;
typedef __attribute__((ext_vector_type(8))) _Float16 f16x8;
typedef __attribute__((ext_vector_type(4))) float f32x4;

#define MFMA(a, b, c) __builtin_amdgcn_mfma_f32_16x16x32_f16((a), (b), (c), 0, 0, 0)

// ---------------------------------------------------------------------------
// prep_weights: convert each W (fp32 256x256) to fp16 in MFMA-B-fragment-
// native tiled order (see round 2). 512KB of d_ws.
// ---------------------------------------------------------------------------
__global__ __launch_bounds__(256) void prep_weights(
    const float* __restrict__ Wq, const float* __restrict__ Wk,
    const float* __restrict__ Wv, const float* __restrict__ Wo,
    f16* __restrict__ wt)
{
    int f = blockIdx.x * 256 + threadIdx.x;      // 0 .. 262143
    int j  = f & 7;
    int l  = (f >> 3) & 63;
    int ks = (f >> 9) & 7;
    int nt = (f >> 12) & 15;
    int m  = f >> 16;
    const float* W = (m == 0) ? Wq : (m == 1) ? Wk : (m == 2) ? Wv : Wo;
    int k   = ks * 32 + ((l >> 4) << 3) + j;
    int col = nt * 16 + (l & 15);
    wt[f] = (f16)W[k * 256 + col];
}

// ---------------------------------------------------------------------------
// fused_attn: one block per sequence, 512 threads (8 waves), 3 barriers/head.
// LDS map (81792 B total -> 2 blocks/CU):
//   Xs  [96][256] f16, 16B-granule XOR swizzle (g ^= row&7)   49152 B
//   Ks  [96][40]  f16  (K for current head)                    7680 B
//   Ps  [96][96]  f16  multi-role region:                     18432 B
//        cols  0..31 : A (PV out, head h-1) read by Wo in phase A
//        cols 48..87 : Q (QKV out) read by S in phase B
//        cols  0..95 : P (softmax out) written in B, read in C
//   VTs [32][96]  f16  (V transposed)                          6144 B
//   rbh [96] f32                                                384 B
// Phase order per head h:
//   A: Wo(h-1) [reads Ps cols0..31] || QKV(h) [writes Q-area,Ks,VTs] ; s1
//   B: S(QK^T)+softmax+P-write [wave w owns row strip w]             ; s2
//   C: PV + A-write [wave w owns strip w: reads P rows, then writes
//      A cols 0..31 of the same rows -- no cross-wave hazard]        ; s3
// waves_per_eu(4,4): pin allocator at 128-VGPR budget (2 blocks/CU is the
// LDS cap anyway); prevents the round-2 squeeze-to-64 that spilled oacc
// (~200MB scratch writes/dispatch).
// ---------------------------------------------------------------------------
__global__ __launch_bounds__(512) __attribute__((amdgpu_waves_per_eu(4, 4)))
void fused_attn(
    const float* __restrict__ Z, const f16* __restrict__ wt,
    const float* __restrict__ rb, float* __restrict__ out)
{
    __shared__ f16 Xs[96 * 256];
    __shared__ f16 Ks[96 * 40];
    __shared__ f16 Ps[96 * 96];
    __shared__ f16 VTs[32 * 96];
    __shared__ float rbh[96];

    const int tid  = threadIdx.x;
    const int n    = blockIdx.x;
    const int w    = tid >> 6;
    const int lane = tid & 63;
    const int g    = lane >> 4;   // 16-lane group 0..3
    const int qr   = lane & 15;

    // ---- stage X as fp16 into LDS, XOR-swizzled 16B granules ----
    const float4* Zv = (const float4*)(Z + (size_t)n * (LSEQ * DM));
#pragma unroll
    for (int r2 = 0; r2 < 12; ++r2) {
        int e = tid + (r2 << 9);          // float4 index 0..6143
        float4 x = Zv[e];
        int row = e >> 6;
        int c4  = e & 63;                 // float4 within row
        int gr  = c4 >> 1;                // 16B granule 0..31
        int hf  = c4 & 1;
        int idx = row * 256 + ((gr ^ (row & 7)) << 3) + hf * 4;
        f16x4 hv = {(f16)x.x, (f16)x.y, (f16)x.z, (f16)x.w};
        *(f16x4*)&Xs[idx] = hv;
    }

    f32x4 oacc[12];
#pragma unroll
    for (int i = 0; i < 12; ++i) oacc[i] = (f32x4){0.f, 0.f, 0.f, 0.f};

    const float scale = 0.17677669529663687f;  // 1/sqrt(32)

    __syncthreads();  // Xs visible

    // Wo accumulate for head hh: A from Ps cols 0..31
    auto wo_acc = [&](int hh) {
        f16x8 afr[6];
#pragma unroll
        for (int m = 0; m < 6; ++m)
            afr[m] = *(const f16x8*)&Ps[(m * 16 + qr) * 96 + g * 8];
#pragma unroll
        for (int ntl = 0; ntl < 2; ++ntl) {
            int nt = w * 2 + ntl;
            const f16x8 bh = *(const f16x8*)(wt +
                (size_t)((((3 * 16 + nt) * 8 + hh) * 64) + lane) * 8);
#pragma unroll
            for (int m = 0; m < 6; ++m)
                oacc[ntl * 6 + m] = MFMA(afr[m], bh, oacc[ntl * 6 + m]);
        }
    };

    for (int h = 0; h < NH; ++h) {
        // ================= phase A: Wo(h-1) + QKV(h) =================
        if (tid < 96) rbh[tid] = rb[h * 96 + tid];
        if (h > 0) wo_acc(h - 1);

        {
            int start = (w < 4) ? w * 5 : 20 + (w - 4) * 4;
            int remaining = (w < 4) ? 5 : 4;
            int t = start;
            while (remaining > 0) {
                int col = t / 6;            // 0..5 (mat*2 + local ncol)
                int m0  = t - col * 6;
                int run = 6 - m0; if (run > remaining) run = remaining;
                int mat = col >> 1;
                int nt  = h * 2 + (col & 1);
                const f16* bp = wt + (size_t)(((mat * 16 + nt) * 8) * 64 + lane) * 8;
                f16x8 B[8];
#pragma unroll
                for (int ks = 0; ks < 8; ++ks)
                    B[ks] = *(const f16x8*)(bp + ((size_t)ks << 9));
                for (int mi = 0; mi < run; ++mi) {
                    int m = m0 + mi;
                    int arow = m * 16 + qr;
                    int rl = arow & 7;
                    const f16* xb = &Xs[arow * 256];
                    f32x4 a0 = {0.f, 0.f, 0.f, 0.f};
                    f32x4 a1 = {0.f, 0.f, 0.f, 0.f};
#pragma unroll
                    for (int ks = 0; ks < 8; ks += 2) {   // two chains of 4
                        a0 = MFMA(*(const f16x8*)&xb[((g + ks * 4) ^ rl) << 3],
                                  B[ks], a0);
                        a1 = MFMA(*(const f16x8*)&xb[((g + (ks + 1) * 4) ^ rl) << 3],
                                  B[ks + 1], a1);
                    }
                    f32x4 acc = a0 + a1;
                    // C frag: col = qr (head-dim), row = m*16 + g*4 + r
                    int cl = (col & 1) * 16 + qr;   // 0..31 within head
                    int i0 = m * 16 + g * 4;
                    if (mat == 0) {          // Q -> Ps cols 48..87
#pragma unroll
                        for (int r = 0; r < 4; ++r)
                            Ps[(i0 + r) * 96 + 48 + cl] = (f16)acc[r];
                    } else if (mat == 1) {   // K -> Ks
#pragma unroll
                        for (int r = 0; r < 4; ++r)
                            Ks[(i0 + r) * 40 + cl] = (f16)acc[r];
                    } else {                 // V -> transposed VTs[c][i]
                        f16x4 vv = {(f16)acc[0], (f16)acc[1], (f16)acc[2], (f16)acc[3]};
                        *(f16x4*)&VTs[cl * 96 + i0] = vv;
                    }
                }
                t += run; remaining -= run;
            }
        }
        __syncthreads();  // s1: Q/K/V visible; Wo(h-1) A-reads complete

        // ============ phase B: S = Q K^T, softmax, P write ============
        if (w < 6) {
            f32x4 sacc[6];
            f16x8 aq = *(const f16x8*)&Ps[(w * 16 + qr) * 96 + 48 + g * 8];
#pragma unroll
            for (int tt = 0; tt < 6; ++tt) {
                f32x4 acc = {0.f, 0.f, 0.f, 0.f};
                acc = MFMA(aq, *(const f16x8*)&Ks[(tt * 16 + qr) * 40 + g * 8], acc);
                sacc[tt] = acc;
            }
            f16 pv[6][4];
#pragma unroll
            for (int r = 0; r < 4; ++r) {
                int i = w * 16 + g * 4 + r;
                float v[6];
                float mx = -3.0e38f;
#pragma unroll
                for (int tt = 0; tt < 6; ++tt) {
                    int j = tt * 16 + qr;
                    int diff = i - j; if (diff < 0) diff += 96;
                    int dc = min(diff, 96 - diff);
                    float val = (dc <= WIN) ? (sacc[tt][r] * scale + rbh[diff]) : -3.0e38f;
                    v[tt] = val;
                    mx = fmaxf(mx, val);
                }
                mx = fmaxf(mx, __shfl_xor(mx, 1));
                mx = fmaxf(mx, __shfl_xor(mx, 2));
                mx = fmaxf(mx, __shfl_xor(mx, 4));
                mx = fmaxf(mx, __shfl_xor(mx, 8));
                float s = 0.f;
#pragma unroll
                for (int tt = 0; tt < 6; ++tt) { float e = __expf(v[tt] - mx); v[tt] = e; s += e; }
                s += __shfl_xor(s, 1);
                s += __shfl_xor(s, 2);
                s += __shfl_xor(s, 4);
                s += __shfl_xor(s, 8);
                float inv = 1.f / s;
#pragma unroll
                for (int tt = 0; tt < 6; ++tt) pv[tt][r] = (f16)(v[tt] * inv);
            }
            // write P rows of OWN strip only (Q cols of this strip already
            // consumed by this wave; no other wave touches these rows)
#pragma unroll
            for (int r = 0; r < 4; ++r) {
                int i = w * 16 + g * 4 + r;
#pragma unroll
                for (int tt = 0; tt < 6; ++tt)
                    Ps[i * 96 + tt * 16 + qr] = pv[tt][r];
            }
        }
        __syncthreads();  // s2: P visible

        // ============ phase C: PV + A-write (strip-exclusive) ============
        if (w < 6) {
            const f16* pp = &Ps[(w * 16 + qr) * 96 + g * 8];
            f16x8 p0 = *(const f16x8*)(pp);
            f16x8 p1 = *(const f16x8*)(pp + 32);
            f16x8 p2 = *(const f16x8*)(pp + 64);
            f32x4 ov[2];
#pragma unroll
            for (int nc = 0; nc < 2; ++nc) {
                const f16* vp = &VTs[(nc * 16 + qr) * 96 + g * 8];
                f32x4 a0 = {0.f, 0.f, 0.f, 0.f};
                f32x4 a1 = {0.f, 0.f, 0.f, 0.f};
                a0 = MFMA(p0, *(const f16x8*)(vp),      a0);
                a1 = MFMA(p1, *(const f16x8*)(vp + 32), a1);
                a0 = MFMA(p2, *(const f16x8*)(vp + 64), a0);
                ov[nc] = a0 + a1;
            }
            // write A into Ps cols 0..31 of OWN rows (reads above done)
#pragma unroll
            for (int nc = 0; nc < 2; ++nc) {
                int i0 = w * 16 + g * 4;
                int c  = nc * 16 + qr;
#pragma unroll
                for (int r = 0; r < 4; ++r)
                    Ps[(i0 + r) * 96 + c] = (f16)ov[nc][r];
            }
        }
        __syncthreads();  // s3: A visible (next phase A reads it)
    }

    // ===== Wo for last head =====
    wo_acc(NH - 1);

    // ===== final store (fp32, coalesced 64B per 16-lane group) =====
    float* on = out + (size_t)n * (LSEQ * DM);
#pragma unroll
    for (int ntl = 0; ntl < 2; ++ntl) {
        int d = (w * 2 + ntl) * 16 + qr;
#pragma unroll
        for (int m = 0; m < 6; ++m) {
#pragma unroll
            for (int r = 0; r < 4; ++r) {
                int i = m * 16 + g * 4 + r;
                on[i * 256 + d] = oacc[ntl * 6 + m][r];
            }
        }
    }
}

extern "C" void kernel_launch(void* const* d_in, const int* in_sizes, int n_in,
                              void* d_out, int out_size, void* d_ws, size_t ws_size,
                              hipStream_t stream) {
    const float* Z  = (const float*)d_in[0];
    const float* Wq = (const float*)d_in[1];
    const float* Wk = (const float*)d_in[2];
    const float* Wv = (const float*)d_in[3];
    const float* Wo = (const float*)d_in[4];
    const float* rbp = (const float*)d_in[5];
    float* out = (float*)d_out;

    f16* wt = (f16*)d_ws;   // 512KB fragment-tiled fp16 weights

    prep_weights<<<1024, 256, 0, stream>>>(Wq, Wk, Wv, Wo, wt);
    fused_attn<<<1024, 512, 0, stream>>>(Z, wt, rbp, out);
}

// Round 5
// 260.796 us; speedup vs baseline: 22.4572x; 1.3041x over previous
//
#include <hip/hip_runtime.h>

#define LSEQ 96
#define DM 256
#define NH 8
#define DH 32
#define WIN 16

typedef unsigned short u16;
typedef unsigned int u32;
typedef _Float16 f16;
typedef __attribute__((ext_vector_type(2))) __fp16 fp16x2_raw;
typedef __attribute__((ext_vector_type(4))) _Float16 f16x4;
typedef __attribute__((ext_vector_type(8))) _Float16 f16x8;
typedef __attribute__((ext_vector_type(4))) float f32x4;
typedef __attribute__((ext_vector_type(4))) u32 u32x4;

#define MFMA(a, b, c) __builtin_amdgcn_mfma_f32_16x16x32_f16((a), (b), (c), 0, 0, 0)

static __device__ __forceinline__ u32 pkrtz(float a, float b) {
    fp16x2_raw t = __builtin_amdgcn_cvt_pkrtz(a, b);
    return __builtin_bit_cast(u32, t);
}
static __device__ __forceinline__ f16x8 mk8(u32 w0, u32 w1, u32 w2, u32 w3) {
    u32x4 t = {w0, w1, w2, w3};
    return __builtin_bit_cast(f16x8, t);
}

// ---------------------------------------------------------------------------
// prep_weights: convert each W (fp32 256x256) to fp16 in MFMA-B-fragment-
// native tiled order:
//   element f = ((mat*16 + ntile)*8 + kstep)*512 + lane*8 + j
//   holds W_mat[k][col],  k = kstep*32 + (lane>>4)*8 + j,  col = ntile*16 + (lane&15)
// As a B-frag this is W[k][col]; read as an A-frag the SAME bytes are W^T.
// 512KB of d_ws.
// ---------------------------------------------------------------------------
__global__ __launch_bounds__(256) void prep_weights(
    const float* __restrict__ Wq, const float* __restrict__ Wk,
    const float* __restrict__ Wv, const float* __restrict__ Wo,
    f16* __restrict__ wt)
{
    int f = blockIdx.x * 256 + threadIdx.x;      // 0 .. 262143
    int j  = f & 7;
    int l  = (f >> 3) & 63;
    int ks = (f >> 9) & 7;
    int nt = (f >> 12) & 15;
    int m  = f >> 16;
    const float* W = (m == 0) ? Wq : (m == 1) ? Wk : (m == 2) ? Wv : Wo;
    int k   = ks * 32 + ((l >> 4) << 3) + j;
    int col = nt * 16 + (l & 15);
    wt[f] = (f16)W[k * 256 + col];
}

// ---------------------------------------------------------------------------
// fused_attn: one block per sequence, 512 threads = 8 waves = 8 heads.
// TWO barriers per block (vs 25 in round 3):
//   stage X -> b1 -> [phase1: K,V all heads (self-cols)] ->
//   [phase2, barrier-free: per-wave head w: Q-on-the-fly, S^T, in-reg
//    softmax, PV, O in regs] -> O-dump into own K cols -> b2 ->
//   [phase3: Wo all waves] -> store.
// LDS (151552 B -> 1 block/CU):
//   Xs [96][256] f16, 16B-granule XOR swizzle (^ row&7)   49152 B
//   KO [96][256] f16, same swizzle; K (cols = head*32+d) then O (same map)
//   VT [256][104] f16 (V^T: row = d-global, col = seq j)  53248 B
// waves_per_eu(2,2): 1 block/CU is the LDS cap anyway; gives the allocator
// the full 256-reg unified budget so phase-2 state (~210) never spills.
// ---------------------------------------------------------------------------
__global__ __attribute__((amdgpu_flat_work_group_size(512, 512),
                          amdgpu_waves_per_eu(2, 2)))
void fused_attn(const float* __restrict__ Z, const f16* __restrict__ wt,
                const float* __restrict__ rb, float* __restrict__ out)
{
    __shared__ f16 Xs[96 * 256];
    __shared__ f16 KO[96 * 256];
    __shared__ f16 VT[256 * 104];

    const int tid  = threadIdx.x;
    const int n    = blockIdx.x;
    const int w    = tid >> 6;        // wave = head
    const int lane = tid & 63;
    const int g    = lane >> 4;       // 16-lane group 0..3
    const int qr   = lane & 15;

    const f32x4 zf4 = {0.f, 0.f, 0.f, 0.f};

    // ---- stage X as fp16, XOR-swizzled 16B granules ----
    const float4* Zv = (const float4*)(Z + (size_t)n * (LSEQ * DM));
#pragma unroll
    for (int r2 = 0; r2 < 12; ++r2) {
        int e = tid + (r2 << 9);
        float4 x = Zv[e];
        int row = e >> 6, c4 = e & 63;
        int gr = c4 >> 1, hf = c4 & 1;
        f16x4 hv = {(f16)x.x, (f16)x.y, (f16)x.z, (f16)x.w};
        *(f16x4*)&Xs[row * 256 + (((gr ^ (row & 7)) << 3) + hf * 4)] = hv;
    }
    __syncthreads();   // b1: Xs visible

    // ===== phase 1: K (mat1), V (mat2), wave w -> col-tiles nt = 2w, 2w+1 ====
#pragma unroll
    for (int mi = 0; mi < 2; ++mi) {
        int mat = 1 + mi;
#pragma unroll
        for (int ntl = 0; ntl < 2; ++ntl) {
            int nt = 2 * w + ntl;
            const f16* bp = wt + (size_t)((mat * 16 + nt) * 8) * 512 + (size_t)lane * 8;
            f16x8 B[8];
#pragma unroll
            for (int ks = 0; ks < 8; ++ks) B[ks] = *(const f16x8*)(bp + ks * 512);
#pragma unroll
            for (int m = 0; m < 6; ++m) {
                int arow = m * 16 + qr, ra = arow & 7;
                const f16* xb = &Xs[arow * 256];
                f32x4 a0 = zf4, a1 = zf4;
#pragma unroll
                for (int ks = 0; ks < 8; ks += 2) {
                    a0 = MFMA(*(const f16x8*)&xb[((4*ks + g) ^ ra) << 3],     B[ks],   a0);
                    a1 = MFMA(*(const f16x8*)&xb[((4*(ks+1) + g) ^ ra) << 3], B[ks+1], a1);
                }
                f32x4 acc = a0 + a1;
                if (mat == 1) {        // K -> KO, row-major swizzled, self cols
                    int col = nt * 16 + qr, gc = col >> 3, cl = col & 7;
#pragma unroll
                    for (int r = 0; r < 4; ++r) {
                        int i = m * 16 + 4 * g + r;
                        KO[i * 256 + ((gc ^ (i & 7)) << 3) + cl] = (f16)acc[r];
                    }
                } else {               // V -> VT[d][j], 4 consecutive j
                    int vrow = nt * 16 + qr;
                    f16x4 vv = {(f16)acc[0], (f16)acc[1], (f16)acc[2], (f16)acc[3]};
                    *(f16x4*)&VT[vrow * 104 + m * 16 + 4 * g] = vv;
                }
            }
        }
    }
    // no barrier: phase 2 reads only this wave's own K/V cols + Xs (b1)

    // ===== phase 2: wave w == head w, barrier-free =====
    f16x8 wq0[8], wq1[8];
    {
        const f16* q0 = wt + (size_t)((2 * w) * 8) * 512 + (size_t)lane * 8;
        const f16* q1 = wt + (size_t)((2 * w + 1) * 8) * 512 + (size_t)lane * 8;
#pragma unroll
        for (int ks = 0; ks < 8; ++ks) {
            wq0[ks] = *(const f16x8*)(q0 + ks * 512);
            wq1[ks] = *(const f16x8*)(q1 + ks * 512);
        }
    }

    // bias table: 24 per-lane values, one per (tile-distance ds, r)
    const float L2E = 1.4426950408889634f;
    const float SC2 = 0.17677669529663687f * L2E;   // (1/sqrt(32))*log2(e)
    float bval[6][4];
#pragma unroll
    for (int ds = 0; ds < 6; ++ds)
#pragma unroll
        for (int r = 0; r < 4; ++r) {
            int diff = 16 * ds + (qr - 4 * g - r);   // (i-j) mod 96, via ds
            if (diff < 0) diff += 96;
            int dc = diff < 96 - diff ? diff : 96 - diff;
            bval[ds][r] = (dc <= WIN) ? rb[w * 96 + diff] * L2E : -1.0e30f;
        }

    const int  sl0 = ((g & 1) << 5) | qr;   // gather source lane (low half)
    const bool ghi = (g >= 2);

    f32x4 osv0[6], osv1[6];

#pragma unroll
    for (int s = 0; s < 6; ++s) {
        // ---- Q^T on the fly: C[d][i] = mfma(A=Wq^T (wt bytes), B=X rows) ----
        int xrow = s * 16 + qr, rx = xrow & 7;
        const f16* xb = &Xs[xrow * 256];
        f32x4 qc0 = zf4, qc1 = zf4;
#pragma unroll
        for (int ks = 0; ks < 8; ++ks) {
            f16x8 xf = *(const f16x8*)&xb[((4 * ks + g) ^ rx) << 3];
            qc0 = MFMA(wq0[ks], xf, qc0);
            qc1 = MFMA(wq1[ks], xf, qc1);
        }
        // lane holds Q[i=16s+qr][d = nc*16 + 4g + r] -> shuffle to B-frag
        u32 q00 = pkrtz(qc0[0], qc0[1]), q01 = pkrtz(qc0[2], qc0[3]);
        u32 q10 = pkrtz(qc1[0], qc1[1]), q11 = pkrtz(qc1[2], qc1[3]);
        u32 a0 = __shfl((int)q00, sl0),      a1 = __shfl((int)q01, sl0);
        u32 a2 = __shfl((int)q00, sl0 + 16), a3 = __shfl((int)q01, sl0 + 16);
        u32 b0 = __shfl((int)q10, sl0),      b1 = __shfl((int)q11, sl0);
        u32 b2 = __shfl((int)q10, sl0 + 16), b3 = __shfl((int)q11, sl0 + 16);
        f16x8 qf = mk8(ghi ? b0 : a0, ghi ? b1 : a1, ghi ? b2 : a2, ghi ? b3 : a3);

        // ---- S^T = mfma(A=K rows, B=Q): lane gets row i=16s+qr, 24 cols ----
        f32x4 st[6];
#pragma unroll
        for (int tt = 0; tt < 6; ++tt) {
            int krow = tt * 16 + qr;
            f16x8 kf = *(const f16x8*)&KO[krow * 256 + (((4 * w + g) ^ (krow & 7)) << 3)];
            st[tt] = MFMA(kf, qf, zf4);
        }

        // ---- masked softmax, in-register (partners: lane^16, lane^32) ----
        float vv[6][4];
        float mx = -3.0e38f;
#pragma unroll
        for (int tt = 0; tt < 6; ++tt) {
#pragma unroll
            for (int r = 0; r < 4; ++r) {
                float vx = st[tt][r] * SC2 + bval[(s - tt + 6) % 6][r];
                vv[tt][r] = vx;
                mx = fmaxf(mx, vx);
            }
        }
        mx = fmaxf(mx, __shfl_xor(mx, 16));
        mx = fmaxf(mx, __shfl_xor(mx, 32));
        float sum = 0.f;
#pragma unroll
        for (int tt = 0; tt < 6; ++tt)
#pragma unroll
            for (int r = 0; r < 4; ++r) {
                float e = __builtin_amdgcn_exp2f(vv[tt][r] - mx);
                vv[tt][r] = e;
                sum += e;
            }
        sum += __shfl_xor(sum, 16);
        sum += __shfl_xor(sum, 32);
        float inv = __builtin_amdgcn_rcpf(sum);
        u32 pk[6][2];
#pragma unroll
        for (int tt = 0; tt < 6; ++tt) {
            pk[tt][0] = pkrtz(vv[tt][0] * inv, vv[tt][1] * inv);
            pk[tt][1] = pkrtz(vv[tt][2] * inv, vv[tt][3] * inv);
        }

        // ---- PV: A = P (shuffled to A-frag), B = V^T rows ----
        f32x4 o0 = zf4, o1 = zf4;
#pragma unroll
        for (int ks = 0; ks < 3; ++ks) {
            u32 c0 = __shfl((int)pk[2*ks][0], sl0),      c1 = __shfl((int)pk[2*ks][1], sl0);
            u32 c2 = __shfl((int)pk[2*ks][0], sl0 + 16), c3 = __shfl((int)pk[2*ks][1], sl0 + 16);
            u32 d0 = __shfl((int)pk[2*ks+1][0], sl0),      d1 = __shfl((int)pk[2*ks+1][1], sl0);
            u32 d2 = __shfl((int)pk[2*ks+1][0], sl0 + 16), d3 = __shfl((int)pk[2*ks+1][1], sl0 + 16);
            f16x8 pf = mk8(ghi ? d0 : c0, ghi ? d1 : c1, ghi ? d2 : c2, ghi ? d3 : c3);
            const f16* vp = &VT[(32 * w + qr) * 104 + 32 * ks + 8 * g];
            o0 = MFMA(pf, *(const f16x8*)vp, o0);
            o1 = MFMA(pf, *(const f16x8*)(vp + 16 * 104), o1);
        }
        osv0[s] = o0;
        osv1[s] = o1;
    }

    // ---- O dump into KO cols [32w, 32w+32) (self region; in-wave ordered) --
#pragma unroll
    for (int s = 0; s < 6; ++s) {
        int col0 = 32 * w + qr, gc0 = col0 >> 3, cl = col0 & 7;
        int gc1 = (col0 + 16) >> 3;
#pragma unroll
        for (int r = 0; r < 4; ++r) {
            int i = 16 * s + 4 * g + r;
            KO[i * 256 + ((gc0 ^ (i & 7)) << 3) + cl] = (f16)osv0[s][r];
            KO[i * 256 + ((gc1 ^ (i & 7)) << 3) + cl] = (f16)osv1[s][r];
        }
    }
    __syncthreads();   // b2: full O visible

    // ===== phase 3: out = O @ Wo, wave w -> out cols [32w, 32w+32) =====
    f16x8 wo0[8], wo1[8];
    {
        const f16* p0 = wt + (size_t)((48 + 2 * w) * 8) * 512 + (size_t)lane * 8;
        const f16* p1 = wt + (size_t)((48 + 2 * w + 1) * 8) * 512 + (size_t)lane * 8;
#pragma unroll
        for (int ks = 0; ks < 8; ++ks) {
            wo0[ks] = *(const f16x8*)(p0 + ks * 512);
            wo1[ks] = *(const f16x8*)(p1 + ks * 512);
        }
    }
    f32x4 oacc0[6], oacc1[6];
#pragma unroll
    for (int m = 0; m < 6; ++m) {
        oacc0[m] = zf4;
        oacc1[m] = zf4;
    }
#pragma unroll
    for (int m = 0; m < 6; ++m) {
        int arow = 16 * m + qr, ra = arow & 7;
        const f16* ab = &KO[arow * 256];
#pragma unroll
        for (int ks = 0; ks < 8; ++ks) {
            f16x8 af = *(const f16x8*)&ab[((4 * ks + g) ^ ra) << 3];
            oacc0[m] = MFMA(af, wo0[ks], oacc0[m]);
            oacc1[m] = MFMA(af, wo1[ks], oacc1[m]);
        }
    }

    // ---- store ----
    float* on = out + (size_t)n * (LSEQ * DM);
    int d0 = 32 * w + qr, d1 = d0 + 16;
#pragma unroll
    for (int m = 0; m < 6; ++m) {
#pragma unroll
        for (int r = 0; r < 4; ++r) {
            int i = 16 * m + 4 * g + r;
            on[i * 256 + d0] = oacc0[m][r];
            on[i * 256 + d1] = oacc1[m][r];
        }
    }
}

extern "C" void kernel_launch(void* const* d_in, const int* in_sizes, int n_in,
                              void* d_out, int out_size, void* d_ws, size_t ws_size,
                              hipStream_t stream) {
    const float* Z  = (const float*)d_in[0];
    const float* Wq = (const float*)d_in[1];
    const float* Wk = (const float*)d_in[2];
    const float* Wv = (const float*)d_in[3];
    const float* Wo = (const float*)d_in[4];
    const float* rbp = (const float*)d_in[5];
    float* out = (float*)d_out;

    f16* wt = (f16*)d_ws;   // 512KB fragment-tiled fp16 weights

    prep_weights<<<1024, 256, 0, stream>>>(Wq, Wk, Wv, Wo, wt);
    fused_attn<<<1024, 512, 0, stream>>>(Z, wt, rbp, out);
}